// Round 13
// baseline (133.098 us; speedup 1.0000x reference)
//
#include <hip/hip_runtime.h>

#define N_NODES 20000
#define N_EDGES 640000
#define HIDDEN  128
#define CAP     96        // max in-degree; Binomial(640K,1/20K) tail @96 ~ e^-45
#define DEG_PAD 16        // one counter per 64B line

typedef unsigned short bf16_t;
typedef __attribute__((ext_vector_type(8))) short short8;            // 8 bf16
typedef __attribute__((ext_vector_type(4))) float floatx4;            // MFMA C/D
typedef float float2v __attribute__((ext_vector_type(2)));

__device__ __forceinline__ bf16_t f2bf(float f) {
    union { float f; unsigned int i; } v; v.f = f;
    unsigned int x = v.i + 0x7FFFu + ((v.i >> 16) & 1u);   // RNE
    return (bf16_t)(x >> 16);
}
// float -> OCP e4m3fn, RNE, FTZ subnormals (values |f|<2^-6 -> 0; fine at our scale)
__device__ __forceinline__ unsigned f2fp8(float f) {
    union { float f; unsigned u; } v; v.f = f;
    unsigned s = (v.u >> 24) & 0x80u;
    unsigned a = v.u & 0x7FFFFFFFu;
    if (a > 0x43E00000u) a = 0x43E00000u;        // clamp to 448 (unreachable for N(0,1))
    a = a + 0x0007FFFFu + ((a >> 20) & 1u);      // RNE at 3-bit mantissa
    int e = (int)(a >> 23) - 120;
    unsigned m = (a >> 20) & 7u;
    unsigned em = (e <= 0) ? 0u : (((unsigned)e << 3) | m);
    if (e > 15) em = 0x7Eu;                      // clamp (unreachable)
    return s | em;
}
// 2x fp8(e4m3) -> 2x f32 from a dword; HI selects bytes 2,3. HW convert on
// gfx950; the builtin's word-select must be a LITERAL constant -> template.
template <bool HI>
__device__ __forceinline__ float2v fp8pair(unsigned w) {
#if defined(__has_builtin) && __has_builtin(__builtin_amdgcn_cvt_pk_f32_fp8)
    return __builtin_amdgcn_cvt_pk_f32_fp8(w, HI);
#else
    unsigned p = HI ? (w >> 16) : (w & 0xFFFFu);
    float2v r;
    {   unsigned b = p & 0xFFu, ss = (b & 0x80u) << 24, em = b & 0x7Fu;
        union { unsigned u; float f; } t; t.u = ss | ((em << 20) + 0x3C000000u);
        r.x = em ? t.f : 0.0f; }
    {   unsigned b = (p >> 8) & 0xFFu, ss = (b & 0x80u) << 24, em = b & 0x7Fu;
        union { unsigned u; float f; } t; t.u = ss | ((em << 20) + 0x3C000000u);
        r.y = em ? t.f : 0.0f; }
    return r;
#endif
}

// --- k1a: pure streaming — feat fp32 -> {bf16, fp8} + Bp weight pack -------
// (R11-verified.) No atomics, no scatter: runs at streaming BW.
__global__ __launch_bounds__(256) void convert_kernel(
        const float* __restrict__ feat,
        const float* __restrict__ Wl,
        const float* __restrict__ Wr,
        bf16_t* __restrict__ feat_bf,
        unsigned char* __restrict__ feat_f8,
        bf16_t* __restrict__ Bp) {
    int t = blockIdx.x * 256 + threadIdx.x;    // 0 .. 639999 exactly
    float4 v = ((const float4*)feat)[t];
    ushort4 o = { f2bf(v.x), f2bf(v.y), f2bf(v.z), f2bf(v.w) };
    ((ushort4*)feat_bf)[t] = o;
    unsigned q = f2fp8(v.x) | (f2fp8(v.y) << 8) | (f2fp8(v.z) << 16) | (f2fp8(v.w) << 24);
    ((unsigned*)feat_f8)[t] = q;
    // Bp pack: 32768 entries (K=256 x N=128); layout per R2-verified form
    if (t < 2 * HIDDEN * HIDDEN) {
        int j    = t & 7;
        int lane = (t >> 3) & 63;
        int nt   = (t >> 9) & 7;
        int kt   = t >> 12;
        int n = nt * 16 + (lane & 15);
        int k = kt * 32 + (lane >> 4) * 8 + j;
        float w = (k < HIDDEN) ? Wl[n * HIDDEN + k] : Wr[n * HIDDEN + (k - HIDDEN)];
        Bp[t] = f2bf(w);
    }
}

// --- k1b: edge binning — 4 edges/lane, 4 independent atomic->store chains --
// (R11-verified.) 4 edges per lane via two coalesced int4 loads quadruples
// in-flight atomic->store chains per lane on the latency-bound path.
__global__ __launch_bounds__(256) void fill_kernel(
        const int* __restrict__ eidx,
        int* __restrict__ deg,                 // pre-zeroed, stride DEG_PAD
        unsigned short* __restrict__ bucket) {
    int t = (blockIdx.x * 256 + threadIdx.x) * 4;   // 625 blocks: exact cover
    int4 s4 = *(const int4*)(eidx + t);
    int4 d4 = *(const int4*)(eidx + N_EDGES + t);
    int p0 = atomicAdd(&deg[d4.x * DEG_PAD], 1);
    int p1 = atomicAdd(&deg[d4.y * DEG_PAD], 1);
    int p2 = atomicAdd(&deg[d4.z * DEG_PAD], 1);
    int p3 = atomicAdd(&deg[d4.w * DEG_PAD], 1);
    if (p0 < CAP) bucket[d4.x * CAP + p0] = (unsigned short)s4.x;
    if (p1 < CAP) bucket[d4.y * CAP + p1] = (unsigned short)s4.y;
    if (p2 < CAP) bucket[d4.z * CAP + p2] = (unsigned short)s4.z;
    if (p3 < CAP) bucket[d4.w * CAP + p3] = (unsigned short)s4.w;
}

// --- k2: agg[i] = mean_{j in N(i)} feat_f8[j] — fp8 rows, 1 line/row -------
// (R10/R11-verified: absmax unchanged at 0.03125.) 8 lane-groups x 8 lanes;
// one uint4 load = 8 rows = 8 lines; HW cvt decode; butterfly reduce.
__global__ __launch_bounds__(256) void agg_kernel(
        const unsigned char* __restrict__ feat_f8,
        const int* __restrict__ deg,
        const unsigned short* __restrict__ bucket,
        bf16_t* __restrict__ agg) {
    int wid  = (blockIdx.x * 256 + threadIdx.x) >> 6;
    int lane = threadIdx.x & 63;
    if (wid >= N_NODES) return;
    int g = lane >> 3;         // neighbor-row group (0..7)
    int c = lane & 7;          // 16B chunk within the 128B fp8 row
    int d_true = deg[wid * DEG_PAD];
    int d = min(d_true, CAP);
    const unsigned short* row = bucket + (size_t)wid * CAP;   // 192B stride
    const uint4* yq = (const uint4*)feat_f8;   // row idx -> 8 uint4 chunks

    float acc[16];
#pragma unroll
    for (int i = 0; i < 16; ++i) acc[i] = 0.f;

#define ACC16(U) { \
    float2v f0 = fp8pair<false>((U).x), f1 = fp8pair<true>((U).x);  \
    float2v f2 = fp8pair<false>((U).y), f3 = fp8pair<true>((U).y);  \
    float2v f4 = fp8pair<false>((U).z), f5 = fp8pair<true>((U).z);  \
    float2v f6 = fp8pair<false>((U).w), f7 = fp8pair<true>((U).w);  \
    acc[0]+=f0.x; acc[1]+=f0.y; acc[2]+=f1.x; acc[3]+=f1.y;         \
    acc[4]+=f2.x; acc[5]+=f2.y; acc[6]+=f3.x; acc[7]+=f3.y;         \
    acc[8]+=f4.x; acc[9]+=f4.y; acc[10]+=f5.x; acc[11]+=f5.y;       \
    acc[12]+=f6.x; acc[13]+=f6.y; acc[14]+=f7.x; acc[15]+=f7.y; }

    int k = 0;
    for (; k + 32 <= d; k += 32) {            // 32 rows / 4 loads in flight
        int i0 = (int)row[k      + g];
        int i1 = (int)row[k + 8  + g];
        int i2 = (int)row[k + 16 + g];
        int i3 = (int)row[k + 24 + g];
        uint4 u0 = yq[i0 * 8 + c];
        uint4 u1 = yq[i1 * 8 + c];
        uint4 u2 = yq[i2 * 8 + c];
        uint4 u3 = yq[i3 * 8 + c];
        ACC16(u0); ACC16(u1); ACC16(u2); ACC16(u3);
    }
    for (; k + 8 <= d; k += 8) {              // 8 rows / 1 load
        int i0 = (int)row[k + g];
        uint4 u0 = yq[i0 * 8 + c];
        ACC16(u0);
    }
    if (k < d) {                              // predicated tail (<8 rows)
        int kk = k + g;
        int ia = (int)row[kk < d ? kk : (d - 1)];
        uint4 u = yq[ia * 8 + c];
        if (kk >= d) { u.x = 0u; u.y = 0u; u.z = 0u; u.w = 0u; }  // fp8 0x00 == 0.0
        ACC16(u);
    }
#undef ACC16

#pragma unroll
    for (int i = 0; i < 16; ++i) {
        acc[i] += __shfl_xor(acc[i], 8);
        acc[i] += __shfl_xor(acc[i], 16);
        acc[i] += __shfl_xor(acc[i], 32);
    }
    if (g == 0) {
        float inv = 1.0f / fmaxf((float)d_true, 1.0f);
        uint4 o1, o2;
        o1.x = (unsigned)f2bf(acc[0] * inv)  | ((unsigned)f2bf(acc[1] * inv)  << 16);
        o1.y = (unsigned)f2bf(acc[2] * inv)  | ((unsigned)f2bf(acc[3] * inv)  << 16);
        o1.z = (unsigned)f2bf(acc[4] * inv)  | ((unsigned)f2bf(acc[5] * inv)  << 16);
        o1.w = (unsigned)f2bf(acc[6] * inv)  | ((unsigned)f2bf(acc[7] * inv)  << 16);
        o2.x = (unsigned)f2bf(acc[8] * inv)  | ((unsigned)f2bf(acc[9] * inv)  << 16);
        o2.y = (unsigned)f2bf(acc[10] * inv) | ((unsigned)f2bf(acc[11] * inv) << 16);
        o2.z = (unsigned)f2bf(acc[12] * inv) | ((unsigned)f2bf(acc[13] * inv) << 16);
        o2.w = (unsigned)f2bf(acc[14] * inv) | ((unsigned)f2bf(acc[15] * inv) << 16);
        uint4* dst = (uint4*)(agg + (size_t)wid * HIDDEN + c * 16);
        dst[0] = o1;
        dst[1] = o2;
    }
}

// --- k3: MFMA GEMM  out = [agg | feat] @ [W_l ; W_r]^T + b  (fp32 out) -----
// (R2-verified form.) A-frag: lane holds A[m=lane&15][k=kt*32+(lane>>4)*8+j];
// kt<4 from agg, kt>=4 from feat_bf. C/D: col=lane&15, row=(lane>>4)*4+r
__global__ __launch_bounds__(256) void gemm_out_kernel(
        const bf16_t* __restrict__ agg,
        const bf16_t* __restrict__ feat_bf,
        const bf16_t* __restrict__ Bp,
        const float* __restrict__ bl,
        float* __restrict__ out) {
    int wid = blockIdx.x * 4 + (threadIdx.x >> 6);   // 16-row M-tile
    if (wid >= N_NODES / 16) return;
    int lane = threadIdx.x & 63;
    int m    = lane & 15;
    int quad = lane >> 4;
    int row0 = wid * 16;

    floatx4 acc[8];
    floatx4 zf = {0.f, 0.f, 0.f, 0.f};
#pragma unroll
    for (int nt = 0; nt < 8; ++nt) acc[nt] = zf;

    const short8* bp = (const short8*)Bp;
#pragma unroll
    for (int kt = 0; kt < 8; ++kt) {
        const bf16_t* abase = (kt < 4)
            ? (agg     + (size_t)(row0 + m) * HIDDEN + kt * 32 + quad * 8)
            : (feat_bf + (size_t)(row0 + m) * HIDDEN + (kt - 4) * 32 + quad * 8);
        short8 afrag = *(const short8*)abase;
#pragma unroll
        for (int nt = 0; nt < 8; ++nt) {
            short8 bfrag = bp[(kt * 8 + nt) * 64 + lane];
            acc[nt] = __builtin_amdgcn_mfma_f32_16x16x32_bf16(afrag, bfrag, acc[nt], 0, 0, 0);
        }
    }
    int col = lane & 15;
#pragma unroll
    for (int nt = 0; nt < 8; ++nt) {
        float b = bl[nt * 16 + col];
#pragma unroll
        for (int r = 0; r < 4; ++r) {
            int row = row0 + quad * 4 + r;
            out[(size_t)row * HIDDEN + nt * 16 + col] = acc[nt][r] + b;
        }
    }
}

extern "C" void kernel_launch(void* const* d_in, const int* in_sizes, int n_in,
                              void* d_out, int out_size, void* d_ws, size_t ws_size,
                              hipStream_t stream) {
    const float* feat = (const float*)d_in[0];
    const int*   eidx = (const int*)d_in[1];
    const float* Wl   = (const float*)d_in[2];
    const float* bl   = (const float*)d_in[3];
    const float* Wr   = (const float*)d_in[4];
    float* out = (float*)d_out;

    // workspace layout (~18 MB; ws is 256 MiB); all sections 16B-aligned
    int*            deg     = (int*)d_ws;                                   // 20000*16 int
    unsigned short* bucket  = (unsigned short*)(deg + N_NODES * DEG_PAD);   // 20000*96 u16
    bf16_t*         Bp      = (bf16_t*)(bucket + (size_t)N_NODES * CAP);    // 32768 bf16
    bf16_t*         feat_bf = Bp + 2 * HIDDEN * HIDDEN;                     // 20000*128 bf16
    bf16_t*         agg     = feat_bf + (size_t)N_NODES * HIDDEN;           // 20000*128 bf16
    unsigned char*  feat_f8 = (unsigned char*)(agg + (size_t)N_NODES * HIDDEN); // 20000*128 u8

    (void)hipMemsetAsync(deg, 0, (size_t)N_NODES * DEG_PAD * sizeof(int), stream);

    convert_kernel<<<N_EDGES / 256, 256, 0, stream>>>(
        feat, Wl, Wr, feat_bf, feat_f8, Bp);
    fill_kernel<<<N_EDGES / 1024, 256, 0, stream>>>(
        eidx, deg, bucket);
    agg_kernel<<<(N_NODES * 64) / 256, 256, 0, stream>>>(
        feat_f8, deg, bucket, agg);
    gemm_out_kernel<<<(N_NODES / 16 + 3) / 4, 256, 0, stream>>>(
        agg, feat_bf, Bp, bl, out);
}